// Round 7
// baseline (126.533 us; speedup 1.0000x reference)
//
#include <hip/hip_runtime.h>
#include <hip/hip_bf16.h>
#include <math.h>
#include <string.h>

typedef __attribute__((ext_vector_type(8))) short bf16x8;
typedef __attribute__((ext_vector_type(4))) float f32x4;
typedef __attribute__((ext_vector_type(2))) float f32x2;
typedef __attribute__((ext_vector_type(4))) unsigned int u32x4;

#define BLK 256

// ws layout:
//   [0, 3072)      : W1 pair-packed fp32. Pair P=(t,p,q) covers neurons
//                    c0 = t*32 + q*8 + 2p, c1 = c0+1. 12 floats at
//                    ((t*4+p)*4+q)*12: {w0e,w0o,w1e,w1o,w2e,w2o,w3e,w3o,
//                                       w4e,w4o,b_e,b_o}  (e=c0, o=c1)
//   [4096, 20480)  : W21/W22 bf16 fragments (16 frags x 1024 B)
// frag F = mat*8 + nt*4 + kt (mat: 0=W21, 1=W22)
// ushort index = F*512 + lane*8 + jj
// value = W[n = nt*16 + (lane&15)][k = kt*32 + (lane>>4)*8 + jj]
//
// GEMM2 uses swapped MFMA operands: D = mfma(Wfrag, h1frag, acc) computes
// C'[n][row]: batch row in C-cols (lane&15), neuron n in C-rows (q*4+reg).
// Head dot-products are lane-local (8 FMA + 2 cross-quad shuffles).

__device__ __forceinline__ unsigned int rne_bf16_bits(float w) {
    unsigned int u = __builtin_bit_cast(unsigned int, w);
    u += 0x7fffu + ((u >> 16) & 1u);
    return u >> 16;
}

__global__ void setup_kernel(const float* __restrict__ W1, const float* __restrict__ b1,
                             const float* __restrict__ W21, const float* __restrict__ W22,
                             float* __restrict__ w1p2, unsigned short* __restrict__ frg)
{
    int t = blockIdx.x * blockDim.x + threadIdx.x;   // 0..4095
    if (t < 64) {
        int P = t;
        int tt = P >> 4, pp = (P >> 2) & 3, qq = P & 3;
        int c0 = tt * 32 + qq * 8 + 2 * pp;
        float* dst = w1p2 + P * 12;
        #pragma unroll
        for (int f = 0; f < 5; ++f) {
            dst[2 * f]     = W1[c0 * 5 + f];
            dst[2 * f + 1] = W1[(c0 + 1) * 5 + f];
        }
        dst[10] = b1[c0];
        dst[11] = b1[c0 + 1];
    }
    for (int e = t; e < 16 * 64 * 8; e += 4096) {
        int F = e >> 9, l = (e >> 3) & 63, j = e & 7;
        int mat = F >> 3, nt = (F >> 2) & 1, kt = F & 3;
        int n = nt * 16 + (l & 15);
        int k = kt * 32 + (l >> 4) * 8 + j;
        const float* W = mat ? W22 : W21;
        frg[e] = (unsigned short)rne_bf16_bits(W[n * 128 + k]);
    }
}

// Block = 4 waves, 128 contiguous rows; each wave does 2 row-tiles of 16.
// 5 blocks/CU (20 waves) for latency hiding — R6 was stall-bound at 3.
__global__ __launch_bounds__(BLK, 5) void barriernet_kernel(
    const float* __restrict__ x,
    const float* __restrict__ mean, const float* __restrict__ stdv,
    const float* __restrict__ b21, const float* __restrict__ b22,
    const float* __restrict__ W31, const float* __restrict__ b31,
    const float* __restrict__ W32, const float* __restrict__ b32,
    const float* __restrict__ w1p2, const u32x4* __restrict__ frg,
    float* __restrict__ out)
{
    __shared__ u32x4 ldsF[1024];    // 16 frags x 64
    __shared__ float ldsX[640];     // 128 rows x 5

    const int tid = threadIdx.x;
    #pragma unroll
    for (int i = 0; i < 4; ++i) ldsF[tid + i * BLK] = frg[tid + i * BLK];
    const float* xblk = x + (size_t)blockIdx.x * 640;
    #pragma unroll
    for (int i = 0; i < 2; ++i) ldsX[tid + i * BLK] = xblk[tid + i * BLK];
    if (tid < 128) ldsX[512 + tid] = xblk[512 + tid];

    const int lane = tid & 63;
    const int wave = tid >> 6;
    const int m    = lane & 15;
    const int q    = lane >> 4;

    float sm_s[5], sm_m[5];
    #pragma unroll
    for (int f = 0; f < 5; ++f) { sm_s[f] = stdv[f]; sm_m[f] = mean[f]; }

    // Per-lane slices: n = nt*16 + q*4 + r  (r = accumulator reg index)
    const f32x4 b21a = *(const f32x4*)(b21 + q * 4);
    const f32x4 b21b = *(const f32x4*)(b21 + 16 + q * 4);
    const f32x4 b22a = *(const f32x4*)(b22 + q * 4);
    const f32x4 b22b = *(const f32x4*)(b22 + 16 + q * 4);
    const f32x4 w31a = *(const f32x4*)(W31 + q * 4);
    const f32x4 w31b = *(const f32x4*)(W31 + 16 + q * 4);
    const f32x4 w32a = *(const f32x4*)(W32 + q * 4);
    const f32x4 w32b = *(const f32x4*)(W32 + 16 + q * 4);
    const float b31s = b31[0], b32s = b32[0];

    __syncthreads();

    const size_t row0 = (size_t)blockIdx.x * 128;

    float xf[2][5];
    #pragma unroll
    for (int T = 0; T < 2; ++T)
        #pragma unroll
        for (int f = 0; f < 5; ++f)
            xf[T][f] = ldsX[(wave * 32 + T * 16 + m) * 5 + f];

    // ---- Phase A: layer 1 (packed f32 pairs) into fragment layout ----
    unsigned int au[2][4][4];
    #pragma unroll
    for (int t = 0; t < 4; ++t) {
        #pragma unroll
        for (int p = 0; p < 4; ++p) {
            const float* base = w1p2 + ((t * 4 + p) * 4 + q) * 12;
            const f32x4 A = *(const f32x4*)(base);
            const f32x4 B = *(const f32x4*)(base + 4);
            const f32x4 C = *(const f32x4*)(base + 8);
            const f32x2 w0 = { A[0], A[1] }, w1 = { A[2], A[3] };
            const f32x2 w2 = { B[0], B[1] }, w3 = { B[2], B[3] };
            const f32x2 w4 = { C[0], C[1] }, bb = { C[2], C[3] };
            #pragma unroll
            for (int T = 0; T < 2; ++T) {
                f32x2 h = bb;
                h = __builtin_elementwise_fma((f32x2){ xf[T][0], xf[T][0] }, w0, h);
                h = __builtin_elementwise_fma((f32x2){ xf[T][1], xf[T][1] }, w1, h);
                h = __builtin_elementwise_fma((f32x2){ xf[T][2], xf[T][2] }, w2, h);
                h = __builtin_elementwise_fma((f32x2){ xf[T][3], xf[T][3] }, w3, h);
                h = __builtin_elementwise_fma((f32x2){ xf[T][4], xf[T][4] }, w4, h);
                h = __builtin_elementwise_max(h, (f32x2){ 0.0f, 0.0f });
                __hip_bfloat162 bp = __float22bfloat162_rn(make_float2(h[0], h[1]));
                unsigned int r;
                memcpy(&r, &bp, 4);                 // even -> low, odd -> high
                au[T][t][p] = r;
            }
        }
    }

    // ---- GEMM2 (transposed): acc[T][c] = W_c . h1_T^T + bias ----
    f32x4 acc[2][4];
    #pragma unroll
    for (int T = 0; T < 2; ++T) {
        acc[T][0] = b21a; acc[T][1] = b21b;
        acc[T][2] = b22a; acc[T][3] = b22b;
    }
    #pragma unroll
    for (int kt = 0; kt < 4; ++kt) {
        bf16x8 bw[4];
        #pragma unroll
        for (int c = 0; c < 4; ++c) {              // c = mat*2 + nt
            const int F = (c >> 1) * 8 + (c & 1) * 4 + kt;
            bw[c] = __builtin_bit_cast(bf16x8, ldsF[F * 64 + lane]);
        }
        #pragma unroll
        for (int T = 0; T < 2; ++T) {
            u32x4 t4 = { au[T][kt][0], au[T][kt][1], au[T][kt][2], au[T][kt][3] };
            bf16x8 a = __builtin_bit_cast(bf16x8, t4);
            #pragma unroll
            for (int c = 0; c < 4; ++c)
                acc[T][c] = __builtin_amdgcn_mfma_f32_16x16x32_bf16(bw[c], a, acc[T][c], 0, 0, 0);
        }
    }

    // ---- Heads: lane-local 8-FMA dot + 2 cross-quad shuffles ----
    #pragma unroll
    for (int T = 0; T < 2; ++T) {
        float s31 = 0.0f, s32 = 0.0f;
        #pragma unroll
        for (int r = 0; r < 4; ++r) {
            s31 = fmaf(fmaxf(acc[T][0][r], 0.0f), w31a[r], s31);
            s31 = fmaf(fmaxf(acc[T][1][r], 0.0f), w31b[r], s31);
            s32 = fmaf(fmaxf(acc[T][2][r], 0.0f), w32a[r], s32);
            s32 = fmaf(fmaxf(acc[T][3][r], 0.0f), w32b[r], s32);
        }
        s31 += __shfl_xor(s31, 16);
        s31 += __shfl_xor(s31, 32);
        s32 += __shfl_xor(s32, 16);
        s32 += __shfl_xor(s32, 32);

        // ---- Epilogue: every lane has row m's sums; lanes 0-15 store ----
        const float x31 = s31 + b31s;
        const float z   = s32 + b32s;
        const float x32 = 4.0f / (1.0f + __expf(-z));
        float x0[5];
        #pragma unroll
        for (int f = 0; f < 5; ++f) x0[f] = fmaf(xf[T][f], sm_s[f], sm_m[f]);
        const float h_ineq = (x0[1] - x0[3]) + x32 * (x0[0] - x0[2] - 1.8f * x0[3]);
        const float u_unc  = -x31;
        const float u      = (1.8f * u_unc <= h_ineq) ? u_unc : (h_ineq / 1.8f);
        if (lane < 16)
            out[row0 + wave * 32 + T * 16 + lane] = u;
    }
}

extern "C" void kernel_launch(void* const* d_in, const int* in_sizes, int n_in,
                              void* d_out, int out_size, void* d_ws, size_t ws_size,
                              hipStream_t stream) {
    const float* x    = (const float*)d_in[0];
    const float* mean = (const float*)d_in[1];
    const float* stdv = (const float*)d_in[2];
    const float* W1   = (const float*)d_in[3];
    const float* b1   = (const float*)d_in[4];
    const float* W21  = (const float*)d_in[5];
    const float* b21  = (const float*)d_in[6];
    const float* W22  = (const float*)d_in[7];
    const float* b22  = (const float*)d_in[8];
    const float* W31  = (const float*)d_in[9];
    const float* b31  = (const float*)d_in[10];
    const float* W32  = (const float*)d_in[11];
    const float* b32  = (const float*)d_in[12];
    float* out = (float*)d_out;

    float* w1p2 = (float*)d_ws;
    unsigned short* frg = (unsigned short*)((char*)d_ws + 4096);

    setup_kernel<<<16, 256, 0, stream>>>(W1, b1, W21, W22, w1p2, frg);

    // 524288 rows / 128 rows-per-block = 4096 blocks
    barriernet_kernel<<<4096, BLK, 0, stream>>>(
        x, mean, stdv, b21, b22, W31, b31, W32, b32,
        w1p2, (const u32x4*)frg, out);
}

// Round 8
// 110.079 us; speedup vs baseline: 1.1495x; 1.1495x over previous
//
#include <hip/hip_runtime.h>
#include <math.h>

typedef __attribute__((ext_vector_type(8))) short bf16x8;
typedef __attribute__((ext_vector_type(4))) float f32x4;
typedef __attribute__((ext_vector_type(4))) unsigned int u32x4;

#define BLK 256

// ws layout:
//   [0, 8192)      : W1 Phase-A MFMA fragments, 8 nt-tiles x 64 lanes x 8 bf16.
//                    Lane (n=l&15, q=l>>4), K-slot j within quad:
//                      q0: {W1h[n][0..4], b1h[n], 0, 0}
//                      q1: {W1l[n][0..4], b1l[n], 0, 0}   (lo residuals)
//                      q2: {W1h[n][0..4], 0, 0, 0}        (for xl side)
//                      q3: zeros
//   [8192, 24576)  : W21/W22 GEMM2 fragments with sigma-permuted K:
//                    frag F = mat*8 + nt2*4 + kt; ushort idx F*512 + l*8 + j;
//                    value = W[n2 = nt2*16 + (l&15)][sigma(kt, l>>4, j)]
//                    sigma(kt,q,j) = 16*(2*kt + (j>>2)) + 4*q + (j&3)
//
// sigma is chosen so a lane's Phase-A outputs D[nt][r] (h1 for neuron
// 16*nt + 4*q + r, batch row m=lane&15) ARE its GEMM2 A-fragment:
// slot (kt,j) = D[2*kt + (j>>2)][j&3]. No shuffles, no LDS handoff.

__device__ __forceinline__ unsigned int rne_bf16_bits(float w) {
    unsigned int u = __builtin_bit_cast(unsigned int, w);
    u += 0x7fffu + ((u >> 16) & 1u);
    return u >> 16;
}
__device__ __forceinline__ float bf16_to_f32(unsigned int bits) {
    return __builtin_bit_cast(float, bits << 16);
}

__global__ void setup_kernel(const float* __restrict__ W1, const float* __restrict__ b1,
                             const float* __restrict__ W21, const float* __restrict__ W22,
                             unsigned short* __restrict__ w1f, unsigned short* __restrict__ frg)
{
    int t = blockIdx.x * blockDim.x + threadIdx.x;   // 0..4095
    {   // W1 Phase-A fragment table (4096 ushorts)
        int e = t;
        int nt = e >> 9, l = (e >> 3) & 63, j = e & 7;
        int n = nt * 16 + (l & 15), q = l >> 4;
        unsigned short v = 0;
        if (q == 0) {
            if (j < 5)       v = (unsigned short)rne_bf16_bits(W1[n * 5 + j]);
            else if (j == 5) v = (unsigned short)rne_bf16_bits(b1[n]);
        } else if (q == 1) {
            if (j < 5) {
                unsigned int h = rne_bf16_bits(W1[n * 5 + j]);
                v = (unsigned short)rne_bf16_bits(W1[n * 5 + j] - bf16_to_f32(h));
            } else if (j == 5) {
                unsigned int h = rne_bf16_bits(b1[n]);
                v = (unsigned short)rne_bf16_bits(b1[n] - bf16_to_f32(h));
            }
        } else if (q == 2) {
            if (j < 5)       v = (unsigned short)rne_bf16_bits(W1[n * 5 + j]);
        }
        w1f[e] = v;
    }
    for (int e = t; e < 16 * 64 * 8; e += 4096) {    // GEMM2 table (8192 ushorts)
        int F = e >> 9, l = (e >> 3) & 63, j = e & 7;
        int mat = F >> 3, nt2 = (F >> 2) & 1, kt = F & 3;
        int n2 = nt2 * 16 + (l & 15), q = l >> 4;
        int ks = 16 * (2 * kt + (j >> 2)) + 4 * q + (j & 3);
        const float* W = mat ? W22 : W21;
        frg[e] = (unsigned short)rne_bf16_bits(W[n2 * 128 + ks]);
    }
}

// Persistent grid: 1024 blocks (4/CU), block = 4 waves = 512 rows.
// Wave: 8 iters x 16 rows. Phase A on MFMA (no per-lane weight stream --
// the R5-R7 54us invariance was vector-L1 return volume on W1 loads).
__global__ __launch_bounds__(BLK, 4) void barriernet_kernel(
    const float* __restrict__ x,
    const float* __restrict__ mean, const float* __restrict__ stdv,
    const float* __restrict__ b21, const float* __restrict__ b22,
    const float* __restrict__ W31, const float* __restrict__ b31,
    const float* __restrict__ W32, const float* __restrict__ b32,
    const u32x4* __restrict__ w1fg, const u32x4* __restrict__ frg,
    float* __restrict__ out, int zero)
{
    __shared__ u32x4 ldsF[1024];    // 16 GEMM2 frags x 64 lanes

    const int tid = threadIdx.x;
    #pragma unroll
    for (int i = 0; i < 4; ++i) ldsF[tid + i * BLK] = frg[tid + i * BLK];

    const int lane = tid & 63;
    const int wave = tid >> 6;
    const int m    = lane & 15;
    const int q    = lane >> 4;

    // W1 Phase-A fragments: deliberately hoisted (32 VGPRs, loop-invariant).
    u32x4 w1f[8];
    #pragma unroll
    for (int nt = 0; nt < 8; ++nt) w1f[nt] = w1fg[nt * 64 + lane];

    float sm_s[5], sm_m[5];
    #pragma unroll
    for (int f = 0; f < 5; ++f) { sm_s[f] = stdv[f]; sm_m[f] = mean[f]; }
    const float b31s = b31[0], b32s = b32[0];

    __syncthreads();

    const size_t wrow0 = (size_t)blockIdx.x * 512 + wave * 128;

    // x prefetch: current iter's row in regs (float4 + float)
    float4 xc4; float xc1;
    {
        const float* p = x + (wrow0 + m) * 5;
        xc4 = *(const float4*)p; xc1 = p[4];
    }

    #pragma unroll 1
    for (int it = 0; it < 8; ++it) {
        // ---- prefetch next iter's x ----
        const int itn = (it < 7) ? it + 1 : 7;
        const float* pn = x + (wrow0 + itn * 16 + m) * 5;
        float4 xn4 = *(const float4*)pn;
        float  xn1 = pn[4];

        const float xf[5] = { xc4.x, xc4.y, xc4.z, xc4.w, xc1 };

        // ---- build Phase-A x B-fragment (hi/lo split + 1.0 bias slot) ----
        unsigned int hb[5], lb[5];
        #pragma unroll
        for (int f = 0; f < 5; ++f) {
            hb[f] = rne_bf16_bits(xf[f]);
            lb[f] = rne_bf16_bits(xf[f] - bf16_to_f32(hb[f]));
        }
        const unsigned int xh01 = hb[0] | (hb[1] << 16);
        const unsigned int xh23 = hb[2] | (hb[3] << 16);
        const unsigned int xh4b = hb[4] | (0x3F80u << 16);   // (xh4, 1.0)
        const unsigned int xl01 = lb[0] | (lb[1] << 16);
        const unsigned int xl23 = lb[2] | (lb[3] << 16);
        const unsigned int xl4  = lb[4];
        const bool ql2 = (q < 2), q2 = (q == 2);
        u32x4 xd;
        xd[0] = ql2 ? xh01 : (q2 ? xl01 : 0u);
        xd[1] = ql2 ? xh23 : (q2 ? xl23 : 0u);
        xd[2] = ql2 ? xh4b : (q2 ? xl4  : 0u);
        xd[3] = 0u;
        const bf16x8 xb = __builtin_bit_cast(bf16x8, xd);

        // ---- Phase A: 8 MFMAs; pack straight into GEMM2 A-fragments ----
        unsigned int au[4][4];
        #pragma unroll
        for (int kt = 0; kt < 4; ++kt) {
            f32x4 z = { 0.0f, 0.0f, 0.0f, 0.0f };
            f32x4 d0 = __builtin_amdgcn_mfma_f32_16x16x32_bf16(
                __builtin_bit_cast(bf16x8, w1f[2 * kt]),     xb, z, 0, 0, 0);
            f32x4 d1 = __builtin_amdgcn_mfma_f32_16x16x32_bf16(
                __builtin_bit_cast(bf16x8, w1f[2 * kt + 1]), xb, z, 0, 0, 0);
            au[kt][0] = rne_bf16_bits(fmaxf(d0[0], 0.0f)) | (rne_bf16_bits(fmaxf(d0[1], 0.0f)) << 16);
            au[kt][1] = rne_bf16_bits(fmaxf(d0[2], 0.0f)) | (rne_bf16_bits(fmaxf(d0[3], 0.0f)) << 16);
            au[kt][2] = rne_bf16_bits(fmaxf(d1[0], 0.0f)) | (rne_bf16_bits(fmaxf(d1[1], 0.0f)) << 16);
            au[kt][3] = rne_bf16_bits(fmaxf(d1[2], 0.0f)) | (rne_bf16_bits(fmaxf(d1[3], 0.0f)) << 16);
        }

        // ---- head/bias constants (in-loop, anti-hoisted: tiny L1 loads) ----
        const float* bz21 = b21 + it * zero;
        const float* bz22 = b22 + it * zero;
        const float* wz31 = W31 + it * zero;
        const float* wz32 = W32 + it * zero;
        f32x4 acc[4];
        acc[0] = *(const f32x4*)(bz21 + q * 4);
        acc[1] = *(const f32x4*)(bz21 + 16 + q * 4);
        acc[2] = *(const f32x4*)(bz22 + q * 4);
        acc[3] = *(const f32x4*)(bz22 + 16 + q * 4);

        // ---- GEMM2: 16 MFMAs, weights from LDS ----
        const int fz = it * zero;
        #pragma unroll
        for (int kt = 0; kt < 4; ++kt) {
            u32x4 t4 = { au[kt][0], au[kt][1], au[kt][2], au[kt][3] };
            const bf16x8 a = __builtin_bit_cast(bf16x8, t4);
            #pragma unroll
            for (int c = 0; c < 4; ++c) {          // c = mat*2 + nt2
                const int F = (c >> 1) * 8 + (c & 1) * 4 + kt;
                const bf16x8 bw = __builtin_bit_cast(bf16x8, ldsF[F * 64 + lane + fz]);
                acc[c] = __builtin_amdgcn_mfma_f32_16x16x32_bf16(bw, a, acc[c], 0, 0, 0);
            }
        }

        // ---- Heads: lane-local dot + 2 cross-quad shuffles ----
        const f32x4 w31a = *(const f32x4*)(wz31 + q * 4);
        const f32x4 w31b = *(const f32x4*)(wz31 + 16 + q * 4);
        const f32x4 w32a = *(const f32x4*)(wz32 + q * 4);
        const f32x4 w32b = *(const f32x4*)(wz32 + 16 + q * 4);
        float s31 = 0.0f, s32 = 0.0f;
        #pragma unroll
        for (int r = 0; r < 4; ++r) {
            s31 = fmaf(fmaxf(acc[0][r], 0.0f), w31a[r], s31);
            s31 = fmaf(fmaxf(acc[1][r], 0.0f), w31b[r], s31);
            s32 = fmaf(fmaxf(acc[2][r], 0.0f), w32a[r], s32);
            s32 = fmaf(fmaxf(acc[3][r], 0.0f), w32b[r], s32);
        }
        s31 += __shfl_xor(s31, 16);
        s31 += __shfl_xor(s31, 32);
        s32 += __shfl_xor(s32, 16);
        s32 += __shfl_xor(s32, 32);

        // ---- Epilogue ----
        const float x31 = s31 + b31s;
        const float z   = s32 + b32s;
        const float x32 = 4.0f / (1.0f + __expf(-z));
        float x0[5];
        #pragma unroll
        for (int f = 0; f < 5; ++f) x0[f] = fmaf(xf[f], sm_s[f], sm_m[f]);
        const float h_ineq = (x0[1] - x0[3]) + x32 * (x0[0] - x0[2] - 1.8f * x0[3]);
        const float u_unc  = -x31;
        const float u      = (1.8f * u_unc <= h_ineq) ? u_unc : (h_ineq / 1.8f);
        if (lane < 16)
            out[wrow0 + it * 16 + lane] = u;

        xc4 = xn4; xc1 = xn1;
    }
}

extern "C" void kernel_launch(void* const* d_in, const int* in_sizes, int n_in,
                              void* d_out, int out_size, void* d_ws, size_t ws_size,
                              hipStream_t stream) {
    const float* x    = (const float*)d_in[0];
    const float* mean = (const float*)d_in[1];
    const float* stdv = (const float*)d_in[2];
    const float* W1   = (const float*)d_in[3];
    const float* b1   = (const float*)d_in[4];
    const float* W21  = (const float*)d_in[5];
    const float* b21  = (const float*)d_in[6];
    const float* W22  = (const float*)d_in[7];
    const float* b22  = (const float*)d_in[8];
    const float* W31  = (const float*)d_in[9];
    const float* b31  = (const float*)d_in[10];
    const float* W32  = (const float*)d_in[11];
    const float* b32  = (const float*)d_in[12];
    float* out = (float*)d_out;

    unsigned short* w1f = (unsigned short*)d_ws;
    unsigned short* frg = (unsigned short*)((char*)d_ws + 8192);

    setup_kernel<<<16, 256, 0, stream>>>(W1, b1, W21, W22, w1f, frg);

    // 524288 rows / 512 rows-per-block = 1024 blocks (4 per CU, persistent)
    barriernet_kernel<<<1024, BLK, 0, stream>>>(
        x, mean, stdv, b21, b22, W31, b31, W32, b32,
        (const u32x4*)w1f, (const u32x4*)frg, out, /*zero=*/0);
}

// Round 9
// 108.013 us; speedup vs baseline: 1.1715x; 1.0191x over previous
//
#include <hip/hip_runtime.h>
#include <hip/hip_bf16.h>
#include <math.h>
#include <string.h>

typedef __attribute__((ext_vector_type(8))) short bf16x8;
typedef __attribute__((ext_vector_type(4))) float f32x4;
typedef __attribute__((ext_vector_type(4))) unsigned int u32x4;

#define BLK 256

// ws layout:
//   [0, 8192)      : W1 Phase-A MFMA fragments, 8 nt-tiles x 64 lanes x 8 bf16.
//                    Lane (n=l&15, q=l>>4), K-slot j within quad:
//                      q0: {W1h[n][0..4], b1h[n], 0, 0}
//                      q1: {W1l[n][0..4], b1l[n], 0, 0}   (lo residuals)
//                      q2: {W1h[n][0..4], 0, 0, 0}        (for xl side)
//                      q3: zeros
//   [8192, 24576)  : W21/W22 GEMM2 fragments with sigma-permuted K:
//                    frag F = mat*8 + nt2*4 + kt; ushort idx F*512 + l*8 + j;
//                    value = W[n2 = nt2*16 + (l&15)][sigma(kt, l>>4, j)]
//                    sigma(kt,q,j) = 16*(2*kt + (j>>2)) + 4*q + (j&3)
//
// sigma makes a lane's Phase-A outputs D[nt][r] BE its GEMM2 A-fragment:
// slot (kt,j) = D[2*kt + (j>>2)][j&3]. No shuffles, no LDS handoff.

__device__ __forceinline__ unsigned int rne_bf16_bits(float w) {
    unsigned int u = __builtin_bit_cast(unsigned int, w);
    u += 0x7fffu + ((u >> 16) & 1u);
    return u >> 16;
}
__device__ __forceinline__ float bf16_to_f32(unsigned int bits) {
    return __builtin_bit_cast(float, bits << 16);
}
__device__ __forceinline__ unsigned int pk_bf16(float lo, float hi) {
    __hip_bfloat162 bp = __float22bfloat162_rn(make_float2(lo, hi));
    unsigned int r; memcpy(&r, &bp, 4);
    return r;                                     // lo -> low 16, hi -> high 16
}

__global__ void setup_kernel(const float* __restrict__ W1, const float* __restrict__ b1,
                             const float* __restrict__ W21, const float* __restrict__ W22,
                             unsigned short* __restrict__ w1f, unsigned short* __restrict__ frg)
{
    int t = blockIdx.x * blockDim.x + threadIdx.x;   // 0..4095
    {   // W1 Phase-A fragment table (4096 ushorts)
        int e = t;
        int nt = e >> 9, l = (e >> 3) & 63, j = e & 7;
        int n = nt * 16 + (l & 15), q = l >> 4;
        unsigned short v = 0;
        if (q == 0) {
            if (j < 5)       v = (unsigned short)rne_bf16_bits(W1[n * 5 + j]);
            else if (j == 5) v = (unsigned short)rne_bf16_bits(b1[n]);
        } else if (q == 1) {
            if (j < 5) {
                unsigned int h = rne_bf16_bits(W1[n * 5 + j]);
                v = (unsigned short)rne_bf16_bits(W1[n * 5 + j] - bf16_to_f32(h));
            } else if (j == 5) {
                unsigned int h = rne_bf16_bits(b1[n]);
                v = (unsigned short)rne_bf16_bits(b1[n] - bf16_to_f32(h));
            }
        } else if (q == 2) {
            if (j < 5)       v = (unsigned short)rne_bf16_bits(W1[n * 5 + j]);
        }
        w1f[e] = v;
    }
    for (int e = t; e < 16 * 64 * 8; e += 4096) {    // GEMM2 table (8192 ushorts)
        int F = e >> 9, l = (e >> 3) & 63, j = e & 7;
        int mat = F >> 3, nt2 = (F >> 2) & 1, kt = F & 3;
        int n2 = nt2 * 16 + (l & 15), q = l >> 4;
        int ks = 16 * (2 * kt + (j >> 2)) + 4 * q + (j & 3);
        const float* W = mat ? W22 : W21;
        frg[e] = (unsigned short)rne_bf16_bits(W[n2 * 128 + ks]);
    }
}

// Persistent-ish grid: 1024 blocks (3/CU at 12 waves), block = 4 waves = 512
// rows. Wave: 4 iters x 32 rows (2 tiles, register-blocked so each LDS
// fragment read feeds 2 MFMAs). Bias/head vectors hoisted to registers
// (loop-invariant; R8's per-iter reloads were an L1 stream).
__global__ __launch_bounds__(BLK, 3) void barriernet_kernel(
    const float* __restrict__ x,
    const float* __restrict__ mean, const float* __restrict__ stdv,
    const float* __restrict__ b21, const float* __restrict__ b22,
    const float* __restrict__ W31, const float* __restrict__ b31,
    const float* __restrict__ W32, const float* __restrict__ b32,
    const u32x4* __restrict__ w1fg, const u32x4* __restrict__ frg,
    float* __restrict__ out, int zero)
{
    __shared__ u32x4 ldsF[1024];    // 16 GEMM2 frags x 64 lanes

    const int tid = threadIdx.x;
    #pragma unroll
    for (int i = 0; i < 4; ++i) ldsF[tid + i * BLK] = frg[tid + i * BLK];

    const int lane = tid & 63;
    const int wave = tid >> 6;
    const int m    = lane & 15;
    const int q    = lane >> 4;

    // W1 Phase-A fragments: deliberately register-resident (32 VGPRs).
    u32x4 w1f[8];
    #pragma unroll
    for (int nt = 0; nt < 8; ++nt) w1f[nt] = w1fg[nt * 64 + lane];

    // Bias/head vectors: loop-invariant, register-resident (32 VGPRs).
    f32x4 bac[4], whv[4];
    bac[0] = *(const f32x4*)(b21 + q * 4);
    bac[1] = *(const f32x4*)(b21 + 16 + q * 4);
    bac[2] = *(const f32x4*)(b22 + q * 4);
    bac[3] = *(const f32x4*)(b22 + 16 + q * 4);
    whv[0] = *(const f32x4*)(W31 + q * 4);
    whv[1] = *(const f32x4*)(W31 + 16 + q * 4);
    whv[2] = *(const f32x4*)(W32 + q * 4);
    whv[3] = *(const f32x4*)(W32 + 16 + q * 4);

    float sm_s[5], sm_m[5];
    #pragma unroll
    for (int f = 0; f < 5; ++f) { sm_s[f] = stdv[f]; sm_m[f] = mean[f]; }
    const float b31s = b31[0], b32s = b32[0];

    __syncthreads();

    const size_t wrow0 = (size_t)blockIdx.x * 512 + wave * 128;

    // x prefetch (both tiles of iter 0)
    float4 xc4[2]; float xc1[2];
    #pragma unroll
    for (int T = 0; T < 2; ++T) {
        const float* p = x + (wrow0 + T * 16 + m) * 5;
        xc4[T] = *(const float4*)p; xc1[T] = p[4];
    }

    #pragma unroll 1
    for (int it = 0; it < 4; ++it) {
        // ---- prefetch next iter's x ----
        const int itn = (it < 3) ? it + 1 : 3;
        float4 xn4[2]; float xn1[2];
        #pragma unroll
        for (int T = 0; T < 2; ++T) {
            const float* pn = x + (wrow0 + itn * 32 + T * 16 + m) * 5;
            xn4[T] = *(const float4*)pn; xn1[T] = pn[4];
        }

        float xf[2][5];
        #pragma unroll
        for (int T = 0; T < 2; ++T) {
            xf[T][0] = xc4[T].x; xf[T][1] = xc4[T].y; xf[T][2] = xc4[T].z;
            xf[T][3] = xc4[T].w; xf[T][4] = xc1[T];
        }

        // ---- Phase A per tile: x B-fragment (hi/lo) + 8 MFMAs + pack ----
        unsigned int au[2][4][4];
        #pragma unroll
        for (int T = 0; T < 2; ++T) {
            unsigned int hb[5], lb[5];
            #pragma unroll
            for (int f = 0; f < 5; ++f) {
                hb[f] = rne_bf16_bits(xf[T][f]);
                lb[f] = rne_bf16_bits(xf[T][f] - bf16_to_f32(hb[f]));
            }
            const unsigned int xh01 = hb[0] | (hb[1] << 16);
            const unsigned int xh23 = hb[2] | (hb[3] << 16);
            const unsigned int xh4b = hb[4] | (0x3F80u << 16);   // (xh4, 1.0)
            const unsigned int xl01 = lb[0] | (lb[1] << 16);
            const unsigned int xl23 = lb[2] | (lb[3] << 16);
            const unsigned int xl4  = lb[4];
            const bool ql2 = (q < 2), q2 = (q == 2);
            u32x4 xd;
            xd[0] = ql2 ? xh01 : (q2 ? xl01 : 0u);
            xd[1] = ql2 ? xh23 : (q2 ? xl23 : 0u);
            xd[2] = ql2 ? xh4b : (q2 ? xl4  : 0u);
            xd[3] = 0u;
            const bf16x8 xb = __builtin_bit_cast(bf16x8, xd);

            #pragma unroll
            for (int kt = 0; kt < 4; ++kt) {
                f32x4 z = { 0.0f, 0.0f, 0.0f, 0.0f };
                f32x4 d0 = __builtin_amdgcn_mfma_f32_16x16x32_bf16(
                    __builtin_bit_cast(bf16x8, w1f[2 * kt]),     xb, z, 0, 0, 0);
                f32x4 d1 = __builtin_amdgcn_mfma_f32_16x16x32_bf16(
                    __builtin_bit_cast(bf16x8, w1f[2 * kt + 1]), xb, z, 0, 0, 0);
                au[T][kt][0] = pk_bf16(fmaxf(d0[0], 0.0f), fmaxf(d0[1], 0.0f));
                au[T][kt][1] = pk_bf16(fmaxf(d0[2], 0.0f), fmaxf(d0[3], 0.0f));
                au[T][kt][2] = pk_bf16(fmaxf(d1[0], 0.0f), fmaxf(d1[1], 0.0f));
                au[T][kt][3] = pk_bf16(fmaxf(d1[2], 0.0f), fmaxf(d1[3], 0.0f));
            }
        }

        // ---- GEMM2: 32 MFMAs, each LDS fragment read feeds 2 (anti-hoisted) ----
        f32x4 acc[2][4];
        #pragma unroll
        for (int T = 0; T < 2; ++T)
            #pragma unroll
            for (int c = 0; c < 4; ++c) acc[T][c] = bac[c];
        const int fz = it * zero;
        #pragma unroll
        for (int kt = 0; kt < 4; ++kt) {
            bf16x8 bw[4];
            #pragma unroll
            for (int c = 0; c < 4; ++c) {          // c = mat*2 + nt2
                const int F = (c >> 1) * 8 + (c & 1) * 4 + kt;
                bw[c] = __builtin_bit_cast(bf16x8, ldsF[F * 64 + lane + fz]);
            }
            #pragma unroll
            for (int T = 0; T < 2; ++T) {
                u32x4 t4 = { au[T][kt][0], au[T][kt][1], au[T][kt][2], au[T][kt][3] };
                const bf16x8 a = __builtin_bit_cast(bf16x8, t4);
                #pragma unroll
                for (int c = 0; c < 4; ++c)
                    acc[T][c] = __builtin_amdgcn_mfma_f32_16x16x32_bf16(bw[c], a, acc[T][c], 0, 0, 0);
            }
        }

        // ---- Heads + epilogue per tile ----
        #pragma unroll
        for (int T = 0; T < 2; ++T) {
            float s31 = 0.0f, s32 = 0.0f;
            #pragma unroll
            for (int r = 0; r < 4; ++r) {
                s31 = fmaf(fmaxf(acc[T][0][r], 0.0f), whv[0][r], s31);
                s31 = fmaf(fmaxf(acc[T][1][r], 0.0f), whv[1][r], s31);
                s32 = fmaf(fmaxf(acc[T][2][r], 0.0f), whv[2][r], s32);
                s32 = fmaf(fmaxf(acc[T][3][r], 0.0f), whv[3][r], s32);
            }
            s31 += __shfl_xor(s31, 16);
            s31 += __shfl_xor(s31, 32);
            s32 += __shfl_xor(s32, 16);
            s32 += __shfl_xor(s32, 32);

            const float x31 = s31 + b31s;
            const float z   = s32 + b32s;
            const float x32 = 4.0f / (1.0f + __expf(-z));
            float x0[5];
            #pragma unroll
            for (int f = 0; f < 5; ++f) x0[f] = fmaf(xf[T][f], sm_s[f], sm_m[f]);
            const float h_ineq = (x0[1] - x0[3]) + x32 * (x0[0] - x0[2] - 1.8f * x0[3]);
            const float u_unc  = -x31;
            const float u      = (1.8f * u_unc <= h_ineq) ? u_unc : (h_ineq / 1.8f);
            if (lane < 16)
                out[wrow0 + it * 32 + T * 16 + lane] = u;
        }

        #pragma unroll
        for (int T = 0; T < 2; ++T) { xc4[T] = xn4[T]; xc1[T] = xn1[T]; }
    }
}

extern "C" void kernel_launch(void* const* d_in, const int* in_sizes, int n_in,
                              void* d_out, int out_size, void* d_ws, size_t ws_size,
                              hipStream_t stream) {
    const float* x    = (const float*)d_in[0];
    const float* mean = (const float*)d_in[1];
    const float* stdv = (const float*)d_in[2];
    const float* W1   = (const float*)d_in[3];
    const float* b1   = (const float*)d_in[4];
    const float* W21  = (const float*)d_in[5];
    const float* b21  = (const float*)d_in[6];
    const float* W22  = (const float*)d_in[7];
    const float* b22  = (const float*)d_in[8];
    const float* W31  = (const float*)d_in[9];
    const float* b31  = (const float*)d_in[10];
    const float* W32  = (const float*)d_in[11];
    const float* b32  = (const float*)d_in[12];
    float* out = (float*)d_out;

    unsigned short* w1f = (unsigned short*)d_ws;
    unsigned short* frg = (unsigned short*)((char*)d_ws + 8192);

    setup_kernel<<<16, 256, 0, stream>>>(W1, b1, W21, W22, w1f, frg);

    // 524288 rows / 512 rows-per-block = 1024 blocks
    barriernet_kernel<<<1024, BLK, 0, stream>>>(
        x, mean, stdv, b21, b22, W31, b31, W32, b32,
        (const u32x4*)w1f, (const u32x4*)frg, out, /*zero=*/0);
}